// Round 1
// baseline (2566.027 us; speedup 1.0000x reference)
//
#include <hip/hip_runtime.h>
#include <math.h>

#define B_  64
#define H_  64
#define W_  64
#define HW  4096   // H_*W_

// ---------------------------------------------------------------------------
// Direct 3x3 conv, stride 1, pad 1. One thread = one output pixel, all COUT
// channels accumulated in registers. Weight loads are wave-uniform (scalar).
// ---------------------------------------------------------------------------
template<int CIN, int COUT, bool RELU, bool HASB>
__global__ __launch_bounds__(256) void conv3x3_k(
    const float* __restrict__ x, const float* __restrict__ wt,
    const float* __restrict__ bias, float* __restrict__ out)
{
    const int tid = threadIdx.x;
    const int pix = blockIdx.x * 256 + tid;     // 16 blocks * 256 = 4096
    const int b   = blockIdx.y;
    const int h   = pix >> 6;
    const int w   = pix & 63;

    float acc[COUT];
#pragma unroll
    for (int o = 0; o < COUT; ++o) acc[o] = HASB ? bias[o] : 0.f;

    const float* xb = x + (size_t)b * CIN * HW;
    for (int ci = 0; ci < CIN; ++ci) {
        const float* xp = xb + (size_t)ci * HW;
#pragma unroll
        for (int ky = 0; ky < 3; ++ky) {
            const int yy = h + ky - 1;
            const bool yok = (yy >= 0) && (yy < H_);
#pragma unroll
            for (int kx = 0; kx < 3; ++kx) {
                const int xx = w + kx - 1;
                const bool ok = yok && (xx >= 0) && (xx < W_);
                const float xv = ok ? xp[yy * W_ + xx] : 0.f;
                const float* wp = wt + (size_t)(ci * 3 + ky) * 3 + kx;
#pragma unroll
                for (int o = 0; o < COUT; ++o)
                    acc[o] += wp[(size_t)o * CIN * 9] * xv;
            }
        }
    }

    float* ob = out + (size_t)b * COUT * HW + pix;
#pragma unroll
    for (int o = 0; o < COUT; ++o) {
        float v = acc[o];
        if (RELU) v = fmaxf(v, 0.f);
        ob[(size_t)o * HW] = v;
    }
}

// ---------------------------------------------------------------------------
// BatchNorm (training mode): per-channel mean / rstd over (B, H, W).
// One block per channel. stats[c] = mean, stats[C+c] = rstd.
// ---------------------------------------------------------------------------
template<int C>
__global__ __launch_bounds__(256) void bn_stats_k(
    const float* __restrict__ x, float* __restrict__ stats)
{
    const int c = blockIdx.x;
    const int tid = threadIdx.x;
    float s = 0.f, s2 = 0.f;
    for (int b = 0; b < B_; ++b) {
        const float* xp = x + ((size_t)b * C + c) * HW;
        for (int i = tid; i < HW; i += 256) {
            const float v = xp[i];
            s += v; s2 += v * v;
        }
    }
    __shared__ float ls[256], ls2[256];
    ls[tid] = s; ls2[tid] = s2;
    __syncthreads();
    for (int st = 128; st > 0; st >>= 1) {
        if (tid < st) { ls[tid] += ls[tid + st]; ls2[tid] += ls2[tid + st]; }
        __syncthreads();
    }
    if (tid == 0) {
        const float n = (float)(B_ * HW);
        const float mean = ls[0] / n;
        const float var  = ls2[0] / n - mean * mean;
        stats[c]     = mean;
        stats[C + c] = rsqrtf(var + 1e-5f);
    }
}

template<int C>
__global__ __launch_bounds__(256) void bn_apply_k(
    const float* __restrict__ x, float* __restrict__ y,
    const float* __restrict__ stats,
    const float* __restrict__ g, const float* __restrict__ be)
{
    const size_t idx = (size_t)blockIdx.x * 256 + threadIdx.x;
    const int c = (int)((idx >> 12) % C);          // HW == 2^12
    const float m = stats[c], r = stats[C + c];
    y[idx] = g[c] * (x[idx] - m) * r + be[c];
}

// ---------------------------------------------------------------------------
// Modulated deformable conv 3x3 (DG=2 groups). One thread = one output pixel,
// all O output channels in registers. om holds [offy(18) | offx(18) | mask(18)]
// channels. Applies bias + ReLU.
// ---------------------------------------------------------------------------
template<int CG, int O>
__global__ __launch_bounds__(256) void deform_k(
    const float* __restrict__ x, const float* __restrict__ om,
    const float* __restrict__ wt, const float* __restrict__ bias,
    float* __restrict__ out)
{
    constexpr int DGn = 2;
    const int tid = threadIdx.x;
    const int pix = blockIdx.x * 256 + tid;
    const int b   = blockIdx.y;
    const int h   = pix >> 6;
    const int w   = pix & 63;

    float acc[O];
#pragma unroll
    for (int o = 0; o < O; ++o) acc[o] = bias[o];

    const float* omb = om + (size_t)b * (3 * DGn * 9) * HW + pix;
    const float* xb  = x + (size_t)b * (DGn * CG) * HW;

    for (int g = 0; g < DGn; ++g) {
        const float* xg = xb + (size_t)g * CG * HW;
#pragma unroll
        for (int k = 0; k < 9; ++k) {
            const int gk = g * 9 + k;
            const float offy = omb[(size_t)gk * HW];
            const float offx = omb[(size_t)(DGn * 9 + gk) * HW];
            const float mraw = omb[(size_t)(2 * DGn * 9 + gk) * HW];
            const float msk  = 1.f / (1.f + expf(-mraw));

            const float py = (float)(h + (k / 3) - 1) + offy;
            const float px = (float)(w + (k % 3) - 1) + offx;
            const float y0f = floorf(py), x0f = floorf(px);
            const float ly = py - y0f, lx = px - x0f;
            const int y0 = (int)y0f, x0 = (int)x0f;
            const int y1 = y0 + 1,  x1 = x0 + 1;

            const bool y0ok = (y0 >= 0) && (y0 < H_);
            const bool y1ok = (y1 >= 0) && (y1 < H_);
            const bool x0ok = (x0 >= 0) && (x0 < W_);
            const bool x1ok = (x1 >= 0) && (x1 < W_);

            float w00 = (1.f - ly) * (1.f - lx) * msk; if (!(y0ok && x0ok)) w00 = 0.f;
            float w01 = (1.f - ly) * lx         * msk; if (!(y0ok && x1ok)) w01 = 0.f;
            float w10 = ly * (1.f - lx)         * msk; if (!(y1ok && x0ok)) w10 = 0.f;
            float w11 = ly * lx                 * msk; if (!(y1ok && x1ok)) w11 = 0.f;

            const int yc0 = min(max(y0, 0), H_ - 1);
            const int yc1 = min(max(y1, 0), H_ - 1);
            const int xc0 = min(max(x0, 0), W_ - 1);
            const int xc1 = min(max(x1, 0), W_ - 1);
            const int i00 = yc0 * W_ + xc0, i01 = yc0 * W_ + xc1;
            const int i10 = yc1 * W_ + xc0, i11 = yc1 * W_ + xc1;

            const float* wk = wt + (size_t)(g * CG) * 9 + k;
            for (int c = 0; c < CG; ++c) {
                const float* xc = xg + (size_t)c * HW;
                const float v = w00 * xc[i00] + w01 * xc[i01] +
                                w10 * xc[i10] + w11 * xc[i11];
                const float* wo = wk + (size_t)c * 9;
#pragma unroll
                for (int o = 0; o < O; ++o)
                    acc[o] += wo[(size_t)o * (DGn * CG * 9)] * v;
            }
        }
    }

    float* ob = out + (size_t)b * O * HW + pix;
#pragma unroll
    for (int o = 0; o < O; ++o)
        ob[(size_t)o * HW] = fmaxf(acc[o], 0.f);
}

// ---------------------------------------------------------------------------
// Head: 2x2 quadrant avg-pool -> FC(256->10) -> softmax. One block per image.
// ---------------------------------------------------------------------------
__global__ __launch_bounds__(256) void head_k(
    const float* __restrict__ em, const float* __restrict__ fcw,
    const float* __restrict__ fcb, float* __restrict__ out)
{
    const int b = blockIdx.x, t = threadIdx.x;
    const int c = t >> 2, qy = (t >> 1) & 1, qx = t & 1;
    const float* p = em + ((size_t)b * 64 + c) * HW + qy * 32 * W_ + qx * 32;
    float s = 0.f;
    for (int yy = 0; yy < 32; ++yy)
#pragma unroll 8
        for (int xx = 0; xx < 32; ++xx)
            s += p[yy * W_ + xx];

    __shared__ float pooled[256];
    __shared__ float logits[10];
    pooled[t] = s * (1.f / 1024.f);
    __syncthreads();
    if (t < 10) {
        float l = fcb[t];
        for (int j = 0; j < 256; ++j) l += fcw[t * 256 + j] * pooled[j];
        logits[t] = l;
    }
    __syncthreads();
    if (t == 0) {
        float mx = logits[0];
        for (int i = 1; i < 10; ++i) mx = fmaxf(mx, logits[i]);
        float e[10]; float sum = 0.f;
        for (int i = 0; i < 10; ++i) { e[i] = expf(logits[i] - mx); sum += e[i]; }
        const float inv = 1.f / sum;
        for (int i = 0; i < 10; ++i) out[b * 10 + i] = e[i] * inv;
    }
}

// ---------------------------------------------------------------------------
extern "C" void kernel_launch(void* const* d_in, const int* in_sizes, int n_in,
                              void* d_out, int out_size, void* d_ws, size_t ws_size,
                              hipStream_t stream)
{
    const float* x       = (const float*)d_in[0];
    const float* conv1_w = (const float*)d_in[1];
    const float* bn1_g   = (const float*)d_in[2];
    const float* bn1_b   = (const float*)d_in[3];
    const float* conv2_w = (const float*)d_in[4];
    const float* conv2_b = (const float*)d_in[5];
    const float* bn2_g   = (const float*)d_in[6];
    const float* bn2_b   = (const float*)d_in[7];
    const float* off1_w  = (const float*)d_in[8];
    const float* off1_b  = (const float*)d_in[9];
    const float* d1_w    = (const float*)d_in[10];
    const float* d1_b    = (const float*)d_in[11];
    const float* bn3_g   = (const float*)d_in[12];
    const float* bn3_b   = (const float*)d_in[13];
    const float* off2_w  = (const float*)d_in[14];
    const float* off2_b  = (const float*)d_in[15];
    const float* d2_w    = (const float*)d_in[16];
    const float* d2_b    = (const float*)d_in[17];
    const float* bn4_g   = (const float*)d_in[18];
    const float* bn4_b   = (const float*)d_in[19];
    const float* fc_w    = (const float*)d_in[20];
    const float* fc_b    = (const float*)d_in[21];

    float* ws = (float*)d_ws;
    float* A  = ws;                    //  64* 8*4096 = 2,097,152 f
    float* Bb = A  + 2097152;          //  64*20*4096 = 5,242,880 f
    float* C  = Bb + 5242880;          //  64*54*4096 = 14,155,776 f
    float* D  = C  + 14155776;         //  64*40*4096 = 10,485,760 f
    float* st = D  + 10485760;         //  stats scratch (<=128 f)

    float* outp = (float*)d_out;
    float* em   = outp + 640;          // [64,64,64,64] fp32

    const dim3 blk(256);
    const dim3 gconv(HW / 256, B_);

    // layer 1: conv(3->8) + relu, bn
    conv3x3_k<3, 8, true, false><<<gconv, blk, 0, stream>>>(x, conv1_w, nullptr, A);
    bn_stats_k<8><<<8, blk, 0, stream>>>(A, st);
    bn_apply_k<8><<<(B_ * 8 * HW) / 256, blk, 0, stream>>>(A, A, st, bn1_g, bn1_b);

    // layer 2: conv(8->20)+bias + relu, bn
    conv3x3_k<8, 20, true, true><<<gconv, blk, 0, stream>>>(A, conv2_w, conv2_b, Bb);
    bn_stats_k<20><<<20, blk, 0, stream>>>(Bb, st);
    bn_apply_k<20><<<(B_ * 20 * HW) / 256, blk, 0, stream>>>(Bb, Bb, st, bn2_g, bn2_b);

    // deform block 1: offsets conv(20->54)+bias, deform(20->40)+bias+relu, bn
    conv3x3_k<20, 54, false, true><<<gconv, blk, 0, stream>>>(Bb, off1_w, off1_b, C);
    deform_k<10, 40><<<gconv, blk, 0, stream>>>(Bb, C, d1_w, d1_b, D);
    bn_stats_k<40><<<40, blk, 0, stream>>>(D, st);
    bn_apply_k<40><<<(B_ * 40 * HW) / 256, blk, 0, stream>>>(D, D, st, bn3_g, bn3_b);

    // deform block 2: offsets conv(40->54)+bias, deform(40->64)+bias+relu, bn
    conv3x3_k<40, 54, false, true><<<gconv, blk, 0, stream>>>(D, off2_w, off2_b, C);
    deform_k<20, 64><<<gconv, blk, 0, stream>>>(D, C, d2_w, d2_b, em);
    bn_stats_k<64><<<64, blk, 0, stream>>>(em, st);
    bn_apply_k<64><<<(B_ * 64 * HW) / 256, blk, 0, stream>>>(em, em, st, bn4_g, bn4_b);

    // head: pool + fc + softmax
    head_k<<<B_, blk, 0, stream>>>(em, fc_w, fc_b, outp);
}

// Round 4
// 1564.987 us; speedup vs baseline: 1.6396x; 1.6396x over previous
//
#include <hip/hip_runtime.h>
#include <math.h>

#define B_  64
#define H_  64
#define W_  64
#define HW  4096   // H_*W_

// ---------------------------------------------------------------------------
// Direct 3x3 conv, stride 1, pad 1, with optional inline BN of the INPUT
// (a*x+c per input channel, OOB taps = 0) and optional bias/ReLU on output.
// Output channels chunked: blockIdx.z picks chunk of CT channels (COUT total).
// One thread = one output pixel.
// ---------------------------------------------------------------------------
template<int CIN, int COUT, int CT, bool RELU, bool HASB, bool INBN>
__global__ __launch_bounds__(256) void conv3x3_k(
    const float* __restrict__ x, const float* __restrict__ wt,
    const float* __restrict__ bias,
    const float* __restrict__ stats, const float* __restrict__ gg,
    const float* __restrict__ bb,
    float* __restrict__ out)
{
    const int tid = threadIdx.x;
    const int pix = blockIdx.x * 256 + tid;     // 16 blocks * 256 = 4096
    const int b   = blockIdx.y;
    const int z   = blockIdx.z;                 // channel chunk
    const int h   = pix >> 6;
    const int w   = pix & 63;

    float acc[CT];
#pragma unroll
    for (int o = 0; o < CT; ++o) acc[o] = HASB ? bias[z * CT + o] : 0.f;

    const float* xb = x + (size_t)b * CIN * HW;
    const float* wz = wt + (size_t)z * CT * CIN * 9;

    for (int ci = 0; ci < CIN; ++ci) {
        float a = 1.f, cc = 0.f;
        if (INBN) {
            const float m = stats[ci], r = stats[CIN + ci];
            a  = gg[ci] * r;
            cc = bb[ci] - gg[ci] * m * r;
        }
        const float* xp = xb + (size_t)ci * HW;
#pragma unroll
        for (int ky = 0; ky < 3; ++ky) {
            const int yy = h + ky - 1;
            const bool yok = (yy >= 0) && (yy < H_);
#pragma unroll
            for (int kx = 0; kx < 3; ++kx) {
                const int xx = w + kx - 1;
                const bool ok = yok && (xx >= 0) && (xx < W_);
                float xv = ok ? xp[yy * W_ + xx] : 0.f;
                if (INBN) xv = ok ? (a * xv + cc) : 0.f;
                const float* wp = wz + (size_t)(ci * 3 + ky) * 3 + kx;
#pragma unroll
                for (int o = 0; o < CT; ++o)
                    acc[o] += wp[(size_t)o * CIN * 9] * xv;
            }
        }
    }

    float* ob = out + (size_t)b * COUT * HW + (size_t)z * CT * HW + pix;
#pragma unroll
    for (int o = 0; o < CT; ++o) {
        float v = acc[o];
        if (RELU) v = fmaxf(v, 0.f);
        ob[(size_t)o * HW] = v;
    }
}

// ---------------------------------------------------------------------------
// BN stats, two-stage. Stage 1: grid (C, SPLIT), each block sums B_/SPLIT
// image-planes of channel c. Stage 2: grid C, one wave reduces SPLIT partials.
// stats[c]=mean, stats[C+c]=rstd.
// ---------------------------------------------------------------------------
template<int C, int SPLIT>
__global__ __launch_bounds__(256) void bn_partial_k(
    const float* __restrict__ x, float* __restrict__ part)
{
    const int c = blockIdx.x, s = blockIdx.y, tid = threadIdx.x;
    constexpr int BPB = B_ / SPLIT;
    float sum = 0.f, sum2 = 0.f;
    for (int bi = 0; bi < BPB; ++bi) {
        const int b = s * BPB + bi;
        const float* xp = x + ((size_t)b * C + c) * HW;
        for (int i = tid * 4; i < HW; i += 1024) {
            const float4 v = *(const float4*)(xp + i);
            sum  += v.x + v.y + v.z + v.w;
            sum2 += v.x * v.x + v.y * v.y + v.z * v.z + v.w * v.w;
        }
    }
    for (int off = 32; off; off >>= 1) {
        sum  += __shfl_down(sum,  off);
        sum2 += __shfl_down(sum2, off);
    }
    __shared__ float ls[4], ls2[4];
    const int wv = tid >> 6;
    if ((tid & 63) == 0) { ls[wv] = sum; ls2[wv] = sum2; }
    __syncthreads();
    if (tid == 0) {
        const int idx = (c * SPLIT + s) * 2;
        part[idx]     = ls[0] + ls[1] + ls[2] + ls[3];
        part[idx + 1] = ls2[0] + ls2[1] + ls2[2] + ls2[3];
    }
}

template<int C, int SPLIT>
__global__ __launch_bounds__(64) void bn_finalize_k(
    const float* __restrict__ part, float* __restrict__ stats)
{
    const int c = blockIdx.x, t = threadIdx.x;
    float s  = (t < SPLIT) ? part[(c * SPLIT + t) * 2]     : 0.f;
    float s2 = (t < SPLIT) ? part[(c * SPLIT + t) * 2 + 1] : 0.f;
    for (int off = 32; off; off >>= 1) {
        s  += __shfl_down(s,  off);
        s2 += __shfl_down(s2, off);
    }
    if (t == 0) {
        const float n = (float)(B_ * HW);
        const float m = s / n;
        const float var = s2 / n - m * m;
        stats[c]     = m;
        stats[C + c] = rsqrtf(var + 1e-5f);
    }
}

// ---------------------------------------------------------------------------
// Modulated deformable conv 3x3 (DG=2), inline BN on the gathered input
// (val = a*gather + c*sum_of_valid_bilinear_weights). Output channels chunked
// by blockIdx.z into OC-sized chunks. bias + ReLU applied.
// ---------------------------------------------------------------------------
template<int CG, int O, int OC>
__global__ __launch_bounds__(256) void deform_k(
    const float* __restrict__ x, const float* __restrict__ om,
    const float* __restrict__ wt, const float* __restrict__ bias,
    const float* __restrict__ stats, const float* __restrict__ gg,
    const float* __restrict__ bb,
    float* __restrict__ out)
{
    constexpr int DGn = 2;
    constexpr int CIN = DGn * CG;
    const int tid = threadIdx.x;
    const int pix = blockIdx.x * 256 + tid;
    const int b   = blockIdx.y;
    const int z   = blockIdx.z;
    const int h   = pix >> 6;
    const int w   = pix & 63;

    float acc[OC];
#pragma unroll
    for (int o = 0; o < OC; ++o) acc[o] = bias[z * OC + o];

    const float* omb = om + (size_t)b * (3 * DGn * 9) * HW + pix;
    const float* xb  = x + (size_t)b * CIN * HW;
    const float* wzb = wt + (size_t)(z * OC) * (DGn * CG * 9);

    for (int g = 0; g < DGn; ++g) {
        const float* xg = xb + (size_t)g * CG * HW;
#pragma unroll
        for (int k = 0; k < 9; ++k) {
            const int gk = g * 9 + k;
            const float offy = omb[(size_t)gk * HW];
            const float offx = omb[(size_t)(DGn * 9 + gk) * HW];
            const float mraw = omb[(size_t)(2 * DGn * 9 + gk) * HW];
            const float msk  = 1.f / (1.f + __expf(-mraw));

            const float py = (float)(h + (k / 3) - 1) + offy;
            const float px = (float)(w + (k % 3) - 1) + offx;
            const float y0f = floorf(py), x0f = floorf(px);
            const float ly = py - y0f, lx = px - x0f;
            const int y0 = (int)y0f, x0 = (int)x0f;
            const int y1 = y0 + 1,  x1 = x0 + 1;

            const bool y0ok = (y0 >= 0) && (y0 < H_);
            const bool y1ok = (y1 >= 0) && (y1 < H_);
            const bool x0ok = (x0 >= 0) && (x0 < W_);
            const bool x1ok = (x1 >= 0) && (x1 < W_);

            float w00 = (1.f - ly) * (1.f - lx) * msk; if (!(y0ok && x0ok)) w00 = 0.f;
            float w01 = (1.f - ly) * lx         * msk; if (!(y0ok && x1ok)) w01 = 0.f;
            float w10 = ly * (1.f - lx)         * msk; if (!(y1ok && x0ok)) w10 = 0.f;
            float w11 = ly * lx                 * msk; if (!(y1ok && x1ok)) w11 = 0.f;
            const float wsum = w00 + w01 + w10 + w11;

            const int yc0 = min(max(y0, 0), H_ - 1);
            const int yc1 = min(max(y1, 0), H_ - 1);
            const int xc0 = min(max(x0, 0), W_ - 1);
            const int xc1 = min(max(x1, 0), W_ - 1);
            const int i00 = yc0 * W_ + xc0, i01 = yc0 * W_ + xc1;
            const int i10 = yc1 * W_ + xc0, i11 = yc1 * W_ + xc1;

            const float* wk = wzb + (size_t)(g * CG) * 9 + k;
            for (int c = 0; c < CG; ++c) {
                const int ch = g * CG + c;
                const float m = stats[ch], r = stats[CIN + ch];
                const float a  = gg[ch] * r;
                const float cc = bb[ch] - gg[ch] * m * r;

                const float* xc = xg + (size_t)c * HW;
                const float gath = w00 * xc[i00] + w01 * xc[i01] +
                                   w10 * xc[i10] + w11 * xc[i11];
                const float v = a * gath + cc * wsum;
                const float* wo = wk + (size_t)c * 9;
#pragma unroll
                for (int o = 0; o < OC; ++o)
                    acc[o] += wo[(size_t)o * (DGn * CG * 9)] * v;
            }
        }
    }

    float* ob = out + (size_t)b * O * HW + (size_t)z * OC * HW + pix;
#pragma unroll
    for (int o = 0; o < OC; ++o)
        ob[(size_t)o * HW] = fmaxf(acc[o], 0.f);
}

// ---------------------------------------------------------------------------
// BN apply in place on em (layer 4), float4 vectorized.
// em = 64*64*4096 floats = 4,194,304 float4 -> grid must be 16384 blocks.
// ---------------------------------------------------------------------------
__global__ __launch_bounds__(256) void bn_apply4_k(
    float* __restrict__ y, const float* __restrict__ stats,
    const float* __restrict__ gg, const float* __restrict__ bb)
{
    const size_t i4 = (size_t)blockIdx.x * 256 + threadIdx.x;  // float4 index
    const int c = (int)((i4 >> 10) & 63);                      // 1024 float4/plane
    const float m = stats[c], r = stats[64 + c];
    const float a = gg[c] * r, cc = bb[c] - gg[c] * m * r;
    float4 v = ((float4*)y)[i4];
    v.x = a * v.x + cc; v.y = a * v.y + cc;
    v.z = a * v.z + cc; v.w = a * v.w + cc;
    ((float4*)y)[i4] = v;
}

// ---------------------------------------------------------------------------
// Quadrant avg-pool: grid (B, C), one wave per quadrant.
// pooled[b*256 + c*4 + q]
// ---------------------------------------------------------------------------
__global__ __launch_bounds__(256) void pool_k(
    const float* __restrict__ em, float* __restrict__ pooled)
{
    const int b = blockIdx.x, c = blockIdx.y, t = threadIdx.x;
    const int q = t >> 6, l = t & 63;
    const float* p = em + ((size_t)b * 64 + c) * HW + (q >> 1) * 32 * W_ + (q & 1) * 32;
    float s = 0.f;
    for (int i = l; i < 1024; i += 64) {
        const int yy = i >> 5, xx = i & 31;
        s += p[yy * W_ + xx];
    }
    for (int off = 32; off; off >>= 1) s += __shfl_down(s, off);
    if (l == 0) pooled[b * 256 + c * 4 + q] = s * (1.f / 1024.f);
}

// ---------------------------------------------------------------------------
// FC(256->10) + softmax. One block (64 threads) per image.
// ---------------------------------------------------------------------------
__global__ __launch_bounds__(64) void fc_k(
    const float* __restrict__ pooled, const float* __restrict__ fcw,
    const float* __restrict__ fcb, float* __restrict__ out)
{
    const int b = blockIdx.x, t = threadIdx.x;
    __shared__ float logits[10];
    if (t < 10) {
        float l = fcb[t];
        const float* p = pooled + b * 256;
        for (int j = 0; j < 256; ++j) l += fcw[t * 256 + j] * p[j];
        logits[t] = l;
    }
    __syncthreads();
    if (t == 0) {
        float mx = logits[0];
        for (int i = 1; i < 10; ++i) mx = fmaxf(mx, logits[i]);
        float e[10]; float sum = 0.f;
        for (int i = 0; i < 10; ++i) { e[i] = __expf(logits[i] - mx); sum += e[i]; }
        const float inv = 1.f / sum;
        for (int i = 0; i < 10; ++i) out[b * 10 + i] = e[i] * inv;
    }
}

// ---------------------------------------------------------------------------
extern "C" void kernel_launch(void* const* d_in, const int* in_sizes, int n_in,
                              void* d_out, int out_size, void* d_ws, size_t ws_size,
                              hipStream_t stream)
{
    const float* x       = (const float*)d_in[0];
    const float* conv1_w = (const float*)d_in[1];
    const float* bn1_g   = (const float*)d_in[2];
    const float* bn1_b   = (const float*)d_in[3];
    const float* conv2_w = (const float*)d_in[4];
    const float* conv2_b = (const float*)d_in[5];
    const float* bn2_g   = (const float*)d_in[6];
    const float* bn2_b   = (const float*)d_in[7];
    const float* off1_w  = (const float*)d_in[8];
    const float* off1_b  = (const float*)d_in[9];
    const float* d1_w    = (const float*)d_in[10];
    const float* d1_b    = (const float*)d_in[11];
    const float* bn3_g   = (const float*)d_in[12];
    const float* bn3_b   = (const float*)d_in[13];
    const float* off2_w  = (const float*)d_in[14];
    const float* off2_b  = (const float*)d_in[15];
    const float* d2_w    = (const float*)d_in[16];
    const float* d2_b    = (const float*)d_in[17];
    const float* bn4_g   = (const float*)d_in[18];
    const float* bn4_b   = (const float*)d_in[19];
    const float* fc_w    = (const float*)d_in[20];
    const float* fc_b    = (const float*)d_in[21];

    // Compact workspace (119.6 MB). A (layer-1 out, dead before C is first
    // written) aliases the start of C.
    float* ws = (float*)d_ws;
    float* Bb = ws;                    // relu(conv2+b): 20 ch = 5,242,880 f
    float* D  = ws + 5242880;          // relu(deform1): 40 ch = 10,485,760 f
    float* C  = ws + 15728640;         // offset maps:   54 ch = 14,155,776 f
    float* A  = C;                     // relu(conv1):    8 ch (aliases C)
    float* sm = ws + 29884416;         // small region
    float* st1 = sm,       *st2 = sm + 16,  *st3 = sm + 56, *st4 = sm + 136;
    float* part   = sm + 264;          // 4096 f
    float* pooled = sm + 4360;         // 16384 f   (end: ws + 29,904,760 f)

    float* outp = (float*)d_out;
    float* em   = outp + 640;          // [64,64,64,64] fp32

    const dim3 blk(256);

    // layer 1: conv(3->8) + relu
    conv3x3_k<3, 8, 8, true, false, false><<<dim3(16, B_, 1), blk, 0, stream>>>(
        x, conv1_w, nullptr, nullptr, nullptr, nullptr, A);
    bn_partial_k<8, 32><<<dim3(8, 32), blk, 0, stream>>>(A, part);
    bn_finalize_k<8, 32><<<8, 64, 0, stream>>>(part, st1);

    // layer 2: conv(8->20)+bias+relu, BN1 inline on input
    conv3x3_k<8, 20, 20, true, true, true><<<dim3(16, B_, 1), blk, 0, stream>>>(
        A, conv2_w, conv2_b, st1, bn1_g, bn1_b, Bb);
    bn_partial_k<20, 32><<<dim3(20, 32), blk, 0, stream>>>(Bb, part);
    bn_finalize_k<20, 32><<<20, 64, 0, stream>>>(part, st2);

    // deform block 1: off-conv(20->54, BN2 inline), deform(20->40, BN2 inline)
    conv3x3_k<20, 54, 27, false, true, true><<<dim3(16, B_, 2), blk, 0, stream>>>(
        Bb, off1_w, off1_b, st2, bn2_g, bn2_b, C);
    deform_k<10, 40, 20><<<dim3(16, B_, 2), blk, 0, stream>>>(
        Bb, C, d1_w, d1_b, st2, bn2_g, bn2_b, D);
    bn_partial_k<40, 32><<<dim3(40, 32), blk, 0, stream>>>(D, part);
    bn_finalize_k<40, 32><<<40, 64, 0, stream>>>(part, st3);

    // deform block 2: off-conv(40->54, BN3 inline), deform(40->64, BN3 inline)
    conv3x3_k<40, 54, 27, false, true, true><<<dim3(16, B_, 2), blk, 0, stream>>>(
        D, off2_w, off2_b, st3, bn3_g, bn3_b, C);
    deform_k<20, 64, 32><<<dim3(16, B_, 2), blk, 0, stream>>>(
        D, C, d2_w, d2_b, st3, bn3_g, bn3_b, em);
    bn_partial_k<64, 32><<<dim3(64, 32), blk, 0, stream>>>(em, part);
    bn_finalize_k<64, 32><<<64, 64, 0, stream>>>(part, st4);

    // layer-4 BN applied in place on em (16384 blocks: 4,194,304 float4s)
    bn_apply4_k<<<16384, blk, 0, stream>>>(em, st4, bn4_g, bn4_b);

    // head
    pool_k<<<dim3(B_, 64), blk, 0, stream>>>(em, pooled);
    fc_k<<<B_, 64, 0, stream>>>(pooled, fc_w, fc_b, outp);
}